// Round 1
// baseline (279.631 us; speedup 1.0000x reference)
//
#include <hip/hip_runtime.h>
#include <hip/hip_fp16.h>

typedef _Float16 half8 __attribute__((ext_vector_type(8)));
typedef float    floatx4 __attribute__((ext_vector_type(4)));
typedef unsigned int uintx4 __attribute__((ext_vector_type(4)));

#define MFMA16(a, b, c) __builtin_amdgcn_mfma_f32_16x16x32_f16((a), (b), (c), 0, 0, 0)

constexpr int T_ = 2048;
constexpr int D_ = 1024;
constexpr int NBATCH = 4;
constexpr int NQ = T_ / 16;   // 128 q-tiles of 16 rows

// LDS layout (bytes)
constexpr unsigned OFF_VS  = 0;       // [32][1024] f16, row-major, XOR-swizzled
constexpr unsigned OFF_VT  = 65536;   // [1024][32] f16, transposed, XOR-swizzled
constexpr unsigned OFF_RED = 131072;  // [8 waves][16 q][32 kv] f32, bank-XORed
constexpr unsigned OFF_P   = 147456;  // [16][32] f16, XOR-swizzled
constexpr unsigned OFF_AL  = 148480;  // [16] f32 per-row rescale alpha
constexpr unsigned OFF_L   = 148544;  // [16] f32 final denominators
constexpr unsigned SMEM_BYTES = 148608;

// ---------------- prep: fp32 -> fp16 cast of V ----------------
__global__ __launch_bounds__(256) void cvt_f32_f16(const float* __restrict__ in,
                                                   _Float16* __restrict__ out) {
  const size_t i = (size_t)blockIdx.x * 256 + threadIdx.x;  // one per 8 elems
  const floatx4* p = (const floatx4*)(in + i * 8);
  floatx4 a = p[0], b = p[1];
  half8 h;
  h[0] = (_Float16)a[0]; h[1] = (_Float16)a[1]; h[2] = (_Float16)a[2]; h[3] = (_Float16)a[3];
  h[4] = (_Float16)b[0]; h[5] = (_Float16)b[1]; h[6] = (_Float16)b[2]; h[7] = (_Float16)b[3];
  *(half8*)(out + i * 8) = h;
}

// ---------------- flash attention, causal, K = V ----------------
template <bool USE_WS>
__global__ __launch_bounds__(512) void attn_kernel(const float* __restrict__ Qg,
                                                   const float* __restrict__ Vg,
                                                   const _Float16* __restrict__ Vh,
                                                   float* __restrict__ Og) {
  extern __shared__ char smem[];
  const int tid  = threadIdx.x;
  const int w    = tid >> 6;        // wave 0..7, owns output dims [128w,128w+128)
  const int l    = tid & 63;
  const int l15  = l & 15;
  const int koff = (l >> 4) * 8;    // frag k-offset within a 32-chunk

  const int bid   = blockIdx.x;
  const int batch = bid & 3;                  // batches round-robin XCD pairs
  const int qt    = (NQ - 1) - (bid >> 2);    // descending work for load balance
  const int qbase = qt * 16;

  const float* Qb = Qg + (size_t)batch * T_ * D_;
  const float* Vb = Vg + (size_t)batch * T_ * D_;
  const _Float16* Vhb = USE_WS ? (Vh + (size_t)batch * T_ * D_) : (const _Float16*)nullptr;

  // ---- Q fragments (wave's 128-dim slice, 4 k-chunks of 32), kept in regs ----
  half8 qfrag[4];
#pragma unroll
  for (int c = 0; c < 4; ++c) {
    const float* src = Qb + (size_t)(qbase + l15) * D_ + w * 128 + c * 32 + koff;
    floatx4 a = *(const floatx4*)src;
    floatx4 b = *(const floatx4*)(src + 4);
    half8 h;
    h[0] = (_Float16)a[0]; h[1] = (_Float16)a[1]; h[2] = (_Float16)a[2]; h[3] = (_Float16)a[3];
    h[4] = (_Float16)b[0]; h[5] = (_Float16)b[1]; h[6] = (_Float16)b[2]; h[7] = (_Float16)b[3];
    qfrag[c] = h;
  }

  floatx4 accO[8];
#pragma unroll
  for (int f = 0; f < 8; ++f) accO[f] = (floatx4){0.f, 0.f, 0.f, 0.f};

  float m_run = -1e30f, l_run = 0.0f;
  const int row_sm = 2 * w + (l >> 5);  // softmax row owned by this lane
  const int kv_sm  = l & 31;

  // staging assignment: 4 row-groups x 128 dim-groups; 8 rows x 8 dims per thread
  const int r0 = (tid >> 7) * 8;
  const int d0 = (tid & 127) * 8;

  const int ntiles = (qbase + 15) / 32 + 1;
  for (int t = 0; t < ntiles; ++t) {
    const int kv0 = t * 32;

    // ---- stage V tile: row-major copy (for QK A-frags) + transposed copy (for PV B-frags)
    uintx4 rowd[8];
    if (USE_WS) {
#pragma unroll
      for (int i = 0; i < 8; ++i)
        rowd[i] = *(const uintx4*)(Vhb + (size_t)(kv0 + r0 + i) * D_ + d0);
    } else {
#pragma unroll
      for (int i = 0; i < 8; ++i) {
        const float* s = Vb + (size_t)(kv0 + r0 + i) * D_ + d0;
        floatx4 a = *(const floatx4*)s;
        floatx4 b = *(const floatx4*)(s + 4);
        half8 h;
        h[0] = (_Float16)a[0]; h[1] = (_Float16)a[1]; h[2] = (_Float16)a[2]; h[3] = (_Float16)a[3];
        h[4] = (_Float16)b[0]; h[5] = (_Float16)b[1]; h[6] = (_Float16)b[2]; h[7] = (_Float16)b[3];
        rowd[i] = *(uintx4*)&h;
      }
    }
#pragma unroll
    for (int i = 0; i < 8; ++i) {
      const int row = r0 + i;
      unsigned byte = (unsigned)(row * 2048 + d0 * 2);
      byte ^= (unsigned)((row & 7) << 4);          // G4 swizzle (both sides)
      *(uintx4*)(smem + OFF_VS + byte) = rowd[i];
    }
#pragma unroll
    for (int j = 0; j < 8; ++j) {                  // 8x8 in-register f16 transpose
      const int dj = j >> 1;
      const unsigned sel = (j & 1) ? 0x07060302u : 0x05040100u;
      uintx4 tv;
#pragma unroll
      for (int k = 0; k < 4; ++k)
        tv[k] = __builtin_amdgcn_perm(rowd[2 * k + 1][dj], rowd[2 * k][dj], sel);
      const int dim = d0 + j;
      unsigned byte = (unsigned)(dim * 64 + r0 * 2);
      byte ^= (unsigned)((dim & 7) << 4);
      *(uintx4*)(smem + OFF_VT + byte) = tv;
    }
    __syncthreads();

    // ---- QK^T swapped: S^T[kv=32][q=16], partial over this wave's 128 dims ----
    floatx4 sfrag[2];
    sfrag[0] = (floatx4){0.f, 0.f, 0.f, 0.f};
    sfrag[1] = (floatx4){0.f, 0.f, 0.f, 0.f};
#pragma unroll
    for (int c = 0; c < 4; ++c) {
#pragma unroll
      for (int f = 0; f < 2; ++f) {
        const int vrow = 16 * f + l15;             // A m-index = kv row
        unsigned byte = (unsigned)(vrow * 2048 + (w * 128 + c * 32 + koff) * 2);
        byte ^= (unsigned)((vrow & 7) << 4);
        half8 av = *(const half8*)(smem + OFF_VS + byte);
        sfrag[f] = MFMA16(av, qfrag[c], sfrag[f]);
      }
    }
    // write partials: red[w][q][kv ^ (q&28)]  (XOR keeps writes 16B-contig, reads conflict-free)
#pragma unroll
    for (int f = 0; f < 2; ++f) {
      const int K0 = 16 * f + (l >> 4) * 4;        // C row = kv within tile
      const unsigned off = (unsigned)(w * 512 + l15 * 32 + (K0 ^ (l15 & 28)));
      *(floatx4*)(smem + OFF_RED + off * 4) = sfrag[f];
    }
    __syncthreads();

    // ---- wave-parallel online softmax: 2 rows/wave, 32 lanes per row ----
    {
      const int qq = row_sm;
      const int kidx = kv_sm ^ (qq & 28);
      const float* rp = (const float*)(smem + OFF_RED) + qq * 32 + kidx;
      float s = 0.0f;
#pragma unroll
      for (int ww = 0; ww < 8; ++ww) s += rp[ww * 512];   // cross-wave D reduction
      const int col = kv0 + kv_sm;
      if (col > qbase + qq) s = -1e30f;                   // causal mask
      float mt = s;
#pragma unroll
      for (int off = 16; off >= 1; off >>= 1) mt = fmaxf(mt, __shfl_xor(mt, off));
      const float mnew = fmaxf(m_run, mt);
      const float al = __expf(m_run - mnew);
      const float p = __expf(s - mnew);
      float rs = p;
#pragma unroll
      for (int off = 16; off >= 1; off >>= 1) rs += __shfl_xor(rs, off);
      l_run = l_run * al + rs;
      m_run = mnew;
      unsigned pb = (unsigned)(qq * 64 + kv_sm * 2);
      pb ^= (unsigned)((qq & 7) << 4);
      *(_Float16*)(smem + OFF_P + pb) = (_Float16)p;
      if (kv_sm == 0) ((float*)(smem + OFF_AL))[qq] = al;
    }
    __syncthreads();

    // ---- rescale O + PV: O[16 q][128 dims] += P[16][32] * V[32][128 slice] ----
    half8 pa;
    {
      unsigned pb = (unsigned)(l15 * 64 + koff * 2);
      pb ^= (unsigned)((l15 & 7) << 4);
      pa = *(const half8*)(smem + OFF_P + pb);     // A-frag: row=q=l15, k=kv
    }
    float arow[4];
#pragma unroll
    for (int r = 0; r < 4; ++r)
      arow[r] = ((const float*)(smem + OFF_AL))[(l >> 4) * 4 + r];
#pragma unroll
    for (int f = 0; f < 8; ++f) {
#pragma unroll
      for (int r = 0; r < 4; ++r) accO[f][r] *= arow[r];
      const int dim = w * 128 + f * 16 + l15;      // B n-index = dim
      unsigned byte = (unsigned)(dim * 64 + koff * 2);
      byte ^= (unsigned)((dim & 7) << 4);
      half8 bv = *(const half8*)(smem + OFF_VT + byte);
      accO[f] = MFMA16(pa, bv, accO[f]);
    }
    __syncthreads();  // protect Vs/VT/P before next tile's staging
  }

  // ---- finalize: broadcast denominators, normalize, store ----
  if (kv_sm == 0) ((float*)(smem + OFF_L))[row_sm] = l_run;
  __syncthreads();
  float linv[4];
#pragma unroll
  for (int r = 0; r < 4; ++r)
    linv[r] = 1.0f / ((const float*)(smem + OFF_L))[(l >> 4) * 4 + r];
  float* Ob = Og + (size_t)batch * T_ * D_ + (size_t)qbase * D_;
#pragma unroll
  for (int f = 0; f < 8; ++f) {
    const int dim = w * 128 + f * 16 + l15;
#pragma unroll
    for (int r = 0; r < 4; ++r) {
      const int rr = (l >> 4) * 4 + r;
      Ob[(size_t)rr * D_ + dim] = accO[f][r] * linv[r];
    }
  }
}

extern "C" void kernel_launch(void* const* d_in, const int* in_sizes, int n_in,
                              void* d_out, int out_size, void* d_ws, size_t ws_size,
                              hipStream_t stream) {
  const float* q = (const float*)d_in[0];
  const float* v = (const float*)d_in[1];
  float* out = (float*)d_out;
  const size_t nelem = (size_t)NBATCH * T_ * D_;  // 8388608

  const bool use_ws = ws_size >= nelem * sizeof(_Float16);
  if (use_ws) {
    _Float16* vh = (_Float16*)d_ws;
    cvt_f32_f16<<<dim3((unsigned)(nelem / (256 * 8))), dim3(256), 0, stream>>>(v, vh);
    hipFuncSetAttribute((const void*)attn_kernel<true>,
                        hipFuncAttributeMaxDynamicSharedMemorySize, SMEM_BYTES);
    attn_kernel<true><<<dim3(NBATCH * NQ), dim3(512), SMEM_BYTES, stream>>>(q, v, vh, out);
  } else {
    hipFuncSetAttribute((const void*)attn_kernel<false>,
                        hipFuncAttributeMaxDynamicSharedMemorySize, SMEM_BYTES);
    attn_kernel<false><<<dim3(NBATCH * NQ), dim3(512), SMEM_BYTES, stream>>>(q, v, nullptr, out);
  }
}

// Round 2
// 262.393 us; speedup vs baseline: 1.0657x; 1.0657x over previous
//
#include <hip/hip_runtime.h>
#include <hip/hip_fp16.h>

typedef _Float16 half8 __attribute__((ext_vector_type(8)));
typedef float    floatx4 __attribute__((ext_vector_type(4)));

#define MFMA16(a, b, c) __builtin_amdgcn_mfma_f32_16x16x32_f16((a), (b), (c), 0, 0, 0)

constexpr int T_ = 2048;
constexpr int D_ = 1024;
constexpr int NB = 4;
constexpr int NSTRIP = 128;         // 16-row q-strips per batch
constexpr int NITEMS = NB * NSTRIP; // 512 work items

__device__ __forceinline__ half8 cvt8(floatx4 a, floatx4 b) {
  half8 h;
  h[0] = (_Float16)a[0]; h[1] = (_Float16)a[1]; h[2] = (_Float16)a[2]; h[3] = (_Float16)a[3];
  h[4] = (_Float16)b[0]; h[5] = (_Float16)b[1]; h[6] = (_Float16)b[2]; h[7] = (_Float16)b[3];
  return h;
}

// ---- prep: reset queue counter; cast V->f16 (Vh) and build transposed VhT[D][T] ----
template <int MODE>
__global__ __launch_bounds__(256) void prep(const float* __restrict__ V,
                                            _Float16* __restrict__ VhT,
                                            _Float16* __restrict__ Vh,
                                            unsigned* cnt) {
  __shared__ _Float16 tile[64][65];  // +1 pad: transpose reads 2-way max (free)
  if (blockIdx.x == 0 && threadIdx.x == 0) *cnt = 0;
  const int bid = blockIdx.x;
  const int b = bid & 3;
  const int tt = (bid >> 2) & 31;   // 64-row t-tile
  const int dd = bid >> 7;          // 64-col d-tile
  const float* Vb = V + ((size_t)b * T_ + tt * 64) * D_ + dd * 64;
#pragma unroll
  for (int k = 0; k < 16; ++k) {
    const int e = k * 256 + threadIdx.x;
    const int r = e >> 6, c = e & 63;
    const _Float16 h = (_Float16)Vb[(size_t)r * D_ + c];
    tile[r][c] = h;
    if (MODE == 2) Vh[((size_t)b * T_ + tt * 64 + r) * D_ + dd * 64 + c] = h;
  }
  __syncthreads();
#pragma unroll
  for (int k = 0; k < 16; ++k) {
    const int e = k * 256 + threadIdx.x;
    const int dr = e >> 6, tc = e & 63;
    VhT[((size_t)b * D_ + dd * 64 + dr) * T_ + tt * 64 + tc] = tile[tc][dr];
  }
}

template <int MODE>
__device__ __forceinline__ half8 loadA(const _Float16* __restrict__ Vhb,
                                       const float* __restrict__ Vb, int row, int col) {
  if (MODE == 2) return *(const half8*)(Vhb + (size_t)row * D_ + col);
  const float* p = Vb + (size_t)row * D_ + col;
  return cvt8(*(const floatx4*)p, *(const floatx4*)(p + 4));
}

template <int MODE>
__device__ __forceinline__ half8 loadB(const _Float16* __restrict__ VhTb,
                                       const float* __restrict__ Vb, int dim, int kv) {
  if (MODE >= 1) return *(const half8*)(VhTb + (size_t)dim * T_ + kv);
  half8 h;  // emergency gather (strided f32 columns)
#pragma unroll
  for (int j = 0; j < 8; ++j) h[j] = (_Float16)Vb[(size_t)(kv + j) * D_ + dim];
  return h;
}

// ---- causal flash attention, K=V, Br=16, Bc=32, frags direct from global f16 ----
template <int MODE>
__global__ __launch_bounds__(512) void attn(const float* __restrict__ Qg,
                                            const float* __restrict__ Vg,
                                            const _Float16* __restrict__ VhTg,
                                            const _Float16* __restrict__ Vhg,
                                            unsigned* cnt, float* __restrict__ Og) {
  __shared__ float RED[8][16][36];   // stride 36: (4q+kv)%32 uniform -> conflict-free
  __shared__ _Float16 Psh[16][32];
  __shared__ float AL[16];
  __shared__ float LL[16];
  __shared__ unsigned itemsh;

  const int tid = threadIdx.x;
  const int w = tid >> 6, l = tid & 63, l15 = l & 15, hi = l >> 4;
  const int koff = hi * 8;
  const int row_sm = 2 * w + (l >> 5);
  const int kv_sm = l & 31;
  int done0 = 0;

  for (;;) {
    int item;
    if (MODE == 0) {
      if (done0) break;
      item = blockIdx.x; done0 = 1;
    } else {
      if (tid == 0) itemsh = atomicAdd(cnt, 1u);
      __syncthreads();
      item = (int)itemsh;
      if (item >= NITEMS) break;
    }
    const int s = (NSTRIP - 1) - (item >> 2);   // LPT: longest strips first
    const int batch = item & 3;
    const int qbase = s * 16;
    const int ntiles = ((qbase + 15) >> 5) + 1;

    const float* Qb = Qg + (size_t)batch * T_ * D_;
    const float* Vb = Vg + (size_t)batch * T_ * D_;
    const _Float16* VhTb = (MODE >= 1) ? VhTg + (size_t)batch * T_ * D_ : (const _Float16*)nullptr;
    const _Float16* Vhb  = (MODE == 2) ? Vhg  + (size_t)batch * T_ * D_ : (const _Float16*)nullptr;

    half8 qfrag[4];
#pragma unroll
    for (int c = 0; c < 4; ++c) {
      const float* p = Qb + (size_t)(qbase + l15) * D_ + w * 128 + c * 32 + koff;
      qfrag[c] = cvt8(*(const floatx4*)p, *(const floatx4*)(p + 4));
    }
    floatx4 accO[8];
#pragma unroll
    for (int f = 0; f < 8; ++f) accO[f] = (floatx4){0.f, 0.f, 0.f, 0.f};
    float m_run = -1e30f, l_run = 0.f;

    for (int t = 0; t < ntiles; ++t) {
      const int kv0 = t * 32;
      // PV B-frags issued first: latency hidden under QK + softmax phases
      half8 bv[8];
#pragma unroll
      for (int f = 0; f < 8; ++f)
        bv[f] = loadB<MODE>(VhTb, Vb, w * 128 + f * 16 + l15, kv0 + koff);

      // QK^T swapped: S^T partial over this wave's 128-dim slice
      floatx4 sf0 = {0.f, 0.f, 0.f, 0.f}, sf1 = {0.f, 0.f, 0.f, 0.f};
#pragma unroll
      for (int c = 0; c < 4; ++c) {
        const int col = w * 128 + c * 32 + koff;
        half8 a0 = loadA<MODE>(Vhb, Vb, kv0 + l15, col);
        half8 a1 = loadA<MODE>(Vhb, Vb, kv0 + 16 + l15, col);
        sf0 = MFMA16(a0, qfrag[c], sf0);
        sf1 = MFMA16(a1, qfrag[c], sf1);
      }
      *(floatx4*)&RED[w][l15][4 * hi]      = sf0;  // q=l15, kv=4*hi..+3 (+16 for sf1)
      *(floatx4*)&RED[w][l15][16 + 4 * hi] = sf1;
      __syncthreads();

      // wave-parallel online softmax: thread owns (row_sm, kv_sm)
      {
        float sv = 0.f;
#pragma unroll
        for (int ww = 0; ww < 8; ++ww) sv += RED[ww][row_sm][kv_sm];
        const int col = kv0 + kv_sm;
        if (col > qbase + row_sm) sv = -1e30f;     // causal mask
        float mt = sv;
#pragma unroll
        for (int off = 16; off; off >>= 1) mt = fmaxf(mt, __shfl_xor(mt, off));
        const float mnew = fmaxf(m_run, mt);
        const float al = __expf(m_run - mnew);
        const float p  = __expf(sv - mnew);
        float rs = p;
#pragma unroll
        for (int off = 16; off; off >>= 1) rs += __shfl_xor(rs, off);
        l_run = l_run * al + rs;
        m_run = mnew;
        Psh[row_sm][kv_sm] = (_Float16)p;
        if (kv_sm == 0) AL[row_sm] = al;
      }
      __syncthreads();

      // PV: O[16 q][128-dim slice] += P[16][32] * V[32][dims]
      const half8 pa = *(const half8*)&Psh[l15][koff];
      float ar[4];
#pragma unroll
      for (int r = 0; r < 4; ++r) ar[r] = AL[4 * hi + r];
#pragma unroll
      for (int f = 0; f < 8; ++f) {
#pragma unroll
        for (int r = 0; r < 4; ++r) accO[f][r] *= ar[r];
        accO[f] = MFMA16(pa, bv[f], accO[f]);
      }
      // no barrier: next tile's RED write is safe (RED consumed before bar2),
      // and Psh/AL rewrites happen only after the next bar1.
    }

    if (kv_sm == 0) LL[row_sm] = l_run;
    __syncthreads();
    float inv[4];
#pragma unroll
    for (int r = 0; r < 4; ++r) inv[r] = 1.0f / LL[4 * hi + r];
    float* Ob = Og + (size_t)batch * T_ * D_ + (size_t)qbase * D_;
#pragma unroll
    for (int f = 0; f < 8; ++f) {
      const int dim = w * 128 + f * 16 + l15;
#pragma unroll
      for (int r = 0; r < 4; ++r)
        Ob[(size_t)(4 * hi + r) * D_ + dim] = accO[f][r] * inv[r];
    }
    __syncthreads();  // protect LL/Psh/AL (and itemsh) before next item
  }
}

extern "C" void kernel_launch(void* const* d_in, const int* in_sizes, int n_in,
                              void* d_out, int out_size, void* d_ws, size_t ws_size,
                              hipStream_t stream) {
  const float* q = (const float*)d_in[0];
  const float* v = (const float*)d_in[1];
  float* out = (float*)d_out;
  const size_t NE = (size_t)NB * T_ * D_;        // 8388608 elems
  const size_t HB = NE * sizeof(_Float16);       // 16 MiB

  if (ws_size >= 2 * HB + 256) {
    _Float16* vt = (_Float16*)d_ws;
    _Float16* vh = (_Float16*)((char*)d_ws + HB);
    unsigned* cnt = (unsigned*)((char*)d_ws + 2 * HB);
    prep<2><<<dim3(2048), dim3(256), 0, stream>>>(v, vt, vh, cnt);
    attn<2><<<dim3(256), dim3(512), 0, stream>>>(q, v, vt, vh, cnt, out);
  } else if (ws_size >= HB + 256) {
    _Float16* vt = (_Float16*)d_ws;
    unsigned* cnt = (unsigned*)((char*)d_ws + HB);
    prep<1><<<dim3(2048), dim3(256), 0, stream>>>(v, vt, nullptr, cnt);
    attn<1><<<dim3(256), dim3(512), 0, stream>>>(q, v, vt, nullptr, cnt, out);
  } else {
    attn<0><<<dim3(NITEMS), dim3(512), 0, stream>>>(q, v, nullptr, nullptr, nullptr, out);
  }
}